// Round 3
// baseline (544.732 us; speedup 1.0000x reference)
//
#include <hip/hip_runtime.h>
#include <cstdint>

// out = G @ (x @ W^T + b)      [8192,8192] @ [8192,128]
// mask is ignored: mask == (G==0), so where(mask,0,G) == G identically.
#define NN 8192   // nodes
#define KD 256    // in_dim
#define HD 128    // hidden

#define SPLITK 8
#define KS (NN / SPLITK)   // 1024 k per block
#define BK 32              // k per pipeline step
#define NSTEP (KS / BK)    // 32 steps

typedef __attribute__((ext_vector_type(4))) float   f32x4;
typedef __attribute__((ext_vector_type(8))) __bf16  bf16x8;
typedef __attribute__((ext_vector_type(8))) unsigned short ushort8;

// fp32 -> bf16 round-to-nearest-even
static __device__ __forceinline__ unsigned short f2bf(float f) {
  unsigned u = __builtin_bit_cast(unsigned, f);
  u += 0x7FFFu + ((u >> 16) & 1u);
  return (unsigned short)(u >> 16);
}

static __device__ __forceinline__ bf16x8 pack8(const float4 a, const float4 b) {
  ushort8 u;
  u[0] = f2bf(a.x); u[1] = f2bf(a.y); u[2] = f2bf(a.z); u[3] = f2bf(a.w);
  u[4] = f2bf(b.x); u[5] = f2bf(b.y); u[6] = f2bf(b.z); u[7] = f2bf(b.w);
  return __builtin_bit_cast(bf16x8, u);
}

#define GLD_LDS16(g, l)                                                        \
  __builtin_amdgcn_global_load_lds(                                            \
      (const __attribute__((address_space(1))) void*)(g),                      \
      (__attribute__((address_space(3))) void*)(l), 16, 0, 0)

// ---------------------------------------------------------------------------
// Kernel A: ht[n][m] = sum_k x[m][k]*W[n][k] + b[n], bf16, [HD][NN].
// 512 blocks x 64 thr (1 wave, 16 rows each). K-loop not unrolled.
// ---------------------------------------------------------------------------
__global__ __launch_bounds__(64) void fc_ht_kernel(
    const float* __restrict__ x, const float* __restrict__ W,
    const float* __restrict__ bias, unsigned short* __restrict__ ht)
{
  const int lane = threadIdx.x & 63;
  const int l15  = lane & 15;
  const int lq   = lane >> 4;
  const int m0   = blockIdx.x * 16;

  f32x4 acc[8];
#pragma unroll
  for (int t = 0; t < 8; ++t) acc[t] = (f32x4)0.0f;

  const float* xr = x + (size_t)(m0 + l15) * KD;
#pragma unroll 1
  for (int s = 0; s < KD / 32; ++s) {
    const int k = s * 32 + lq * 8;
    const bf16x8 af = pack8(*(const float4*)(xr + k), *(const float4*)(xr + k + 4));
#pragma unroll
    for (int t = 0; t < 8; ++t) {
      const float* wr = W + (size_t)(t * 16 + l15) * KD + k;
      const bf16x8 bfr = pack8(*(const float4*)wr, *(const float4*)(wr + 4));
      acc[t] = __builtin_amdgcn_mfma_f32_16x16x32_bf16(af, bfr, acc[t], 0, 0, 0);
    }
  }

  // C/D layout: col = lane&15, row = (lane>>4)*4 + reg.
#pragma unroll
  for (int t = 0; t < 8; ++t) {
    const int n  = t * 16 + l15;
    const float bv = bias[n];
    const int mr = m0 + lq * 4;
    uint2 v;
    v.x = (unsigned)f2bf(acc[t][0] + bv) | ((unsigned)f2bf(acc[t][1] + bv) << 16);
    v.y = (unsigned)f2bf(acc[t][2] + bv) | ((unsigned)f2bf(acc[t][3] + bv) << 16);
    *(uint2*)(ht + (size_t)n * NN + mr) = v;
  }
}

// ---------------------------------------------------------------------------
// Kernel B: P[ks] += G_tile @ ht^T, m97-style LDS pipeline.
// 1024 blocks = 128 M-tiles x SPLITK, 256 thr (4 waves), 64x128 tile.
// Both staged tiles are XOR-swizzled on the GLOBAL side (LDS side of
// global_load_lds is forced wave-linear):
//   G  (64 rows x 8 chunks):  phys chunk c holds global chunk c ^ (r&7)
//   ht (128 rows x 4 chunks): phys chunk c holds global chunk c ^ ((r>>1)&3)
// Read-side bank aliasing is exactly 2-way for both (free, m136).
// Split-K partials go to d_ws with plain stores; reduce_kernel sums them.
// ---------------------------------------------------------------------------
__global__ __launch_bounds__(256, 4) void spmm_kernel(
    const float* __restrict__ G, const unsigned short* __restrict__ ht,
    float* __restrict__ P)
{
  __shared__ float          gsh[2][64 * BK];   // 8 KB per buffer
  __shared__ unsigned short hsh[2][HD * BK];   // 8 KB per buffer

  const int tid   = threadIdx.x;
  const int lane  = tid & 63;
  const int wave  = tid >> 6;
  const int l15   = lane & 15;
  const int lq    = lane >> 4;
  const int mtile = blockIdx.x >> 3;   // 0..127
  const int ks    = blockIdx.x & 7;
  const int m0    = mtile * 64;
  const int kb0   = ks * KS;

  f32x4 acc[8];
#pragma unroll
  for (int t = 0; t < 8; ++t) acc[t] = (f32x4)0.0f;

#define STAGE(s_, buf_)                                                         \
  do {                                                                          \
    const int kb = kb0 + (s_) * BK;                                             \
    _Pragma("unroll")                                                           \
    for (int i = 0; i < 2; ++i) {                                               \
      const int e = i * 256 + tid;                                              \
      const int r = e >> 3, c = e & 7;                                          \
      GLD_LDS16(G + (size_t)(m0 + r) * NN + kb + ((c ^ (r & 7)) * 4),           \
                &gsh[buf_][e * 4]);                                             \
    }                                                                           \
    _Pragma("unroll")                                                           \
    for (int i = 0; i < 2; ++i) {                                               \
      const int e = i * 256 + tid;                                              \
      const int r = e >> 2, c = e & 3;                                          \
      GLD_LDS16(ht + (size_t)r * NN + kb + ((c ^ ((r >> 1) & 3)) * 8),          \
                &hsh[buf_][e * 8]);                                             \
    }                                                                           \
  } while (0)

  STAGE(0, 0);

  // read-side swizzled chunk indices (loop-invariant)
  const int gsw0 = (lq * 2 + 0) ^ (l15 & 7);      // G chunk j=0
  const int gsw1 = (lq * 2 + 1) ^ (l15 & 7);      // G chunk j=1
  const int hsw  = lq ^ ((l15 >> 1) & 3);         // ht chunk
  const int gr   = wave * 16 + l15;               // G row within tile

#pragma unroll 1
  for (int s = 0; s < NSTEP; ++s) {
    __syncthreads();                      // vmcnt(0) drain: buf[s&1] ready
    if (s + 1 < NSTEP) STAGE(s + 1, (s + 1) & 1);

    const int b = s & 1;
    const float4 ga0 = *(const float4*)&gsh[b][gr * 32 + gsw0 * 4];
    const float4 ga1 = *(const float4*)&gsh[b][gr * 32 + gsw1 * 4];
    const bf16x8 af = pack8(ga0, ga1);

    uint4 hb[8];
#pragma unroll
    for (int t = 0; t < 8; ++t)
      hb[t] = *(const uint4*)&hsh[b][(t * 16 + l15) * BK + hsw * 8];
#pragma unroll
    for (int t = 0; t < 8; ++t)
      acc[t] = __builtin_amdgcn_mfma_f32_16x16x32_bf16(
          af, __builtin_bit_cast(bf16x8, hb[t]), acc[t], 0, 0, 0);
  }

  // epilogue: plain stores of split-K partials, P[ks][m][n]
  const int mr = m0 + wave * 16 + lq * 4;
  float* __restrict__ pp = P + ((size_t)ks * NN + mr) * HD;
#pragma unroll
  for (int t = 0; t < 8; ++t) {
    const int n = t * 16 + l15;
#pragma unroll
    for (int r = 0; r < 4; ++r)
      pp[(size_t)r * HD + n] = acc[t][r];
  }
}

// ---------------------------------------------------------------------------
// Kernel C: out[m][n] = sum_ks P[ks][m][n].  36 MB traffic, ~6 us.
// ---------------------------------------------------------------------------
__global__ __launch_bounds__(256) void reduce_kernel(
    const f32x4* __restrict__ P, f32x4* __restrict__ out)
{
  const int idx = blockIdx.x * 256 + threadIdx.x;   // 0..262143 float4s
  const int S = NN * HD / 4;
  f32x4 s = P[idx];
#pragma unroll
  for (int k = 1; k < SPLITK; ++k) s += P[(size_t)k * S + idx];
  out[idx] = s;
}

extern "C" void kernel_launch(void* const* d_in, const int* in_sizes, int n_in,
                              void* d_out, int out_size, void* d_ws, size_t ws_size,
                              hipStream_t stream) {
  const float* x = (const float*)d_in[0];
  const float* G = (const float*)d_in[1];
  // d_in[2] = mask: NEVER read. mask == (G==0) => where(mask,0,G) == G.
  const float* W = (const float*)d_in[3];
  const float* b = (const float*)d_in[4];
  float* out = (float*)d_out;

  unsigned short* ht = (unsigned short*)d_ws;                  // 2 MB
  float* P = (float*)((char*)d_ws + (4u << 20));               // 32 MB partials

  fc_ht_kernel<<<NN / 16, 64, 0, stream>>>(x, W, b, ht);
  spmm_kernel<<<(NN / 64) * SPLITK, 256, 0, stream>>>(G, ht, P);
  reduce_kernel<<<NN * HD / 4 / 256, 256, 0, stream>>>((const f32x4*)P, (f32x4*)out);
}